// Round 9
// baseline (737.305 us; speedup 1.0000x reference)
//
#include <hip/hip_runtime.h>

#define T_DIM 512
#define B_DIM 512
#define OBS_DIM 128
#define H_DIM 128
#define A_DIM 18
#define G3 384
#define LDSS 136        // LDS row stride in halfs (128 + 8 pad, 16B-aligned rows)

// exp-argument scales folded into weights/biases/stored gi:
//  r,z gates: arg' = -log2e * arg   (sigmoid(x) = 1/(1+2^(arg')))
//  n gate:    arg' = 2*log2e * arg  (tanh(x) = (2^(arg')-1)/(2^(arg')+1))
#define SC_R (-1.44269504088896f)
#define SC_N (2.88539008177793f)

typedef _Float16 v8h __attribute__((ext_vector_type(8)));
typedef _Float16 v4h __attribute__((ext_vector_type(4)));
typedef float v4f __attribute__((ext_vector_type(4)));

#define EXP2F(x) __builtin_amdgcn_exp2f(x)
#define RCPF(x)  __builtin_amdgcn_rcpf(x)

// LDS-only barrier: drains lgkmcnt but leaves vmcnt in flight.
#define BAR() asm volatile("s_waitcnt lgkmcnt(0)\n\ts_barrier" ::: "memory")

// ---------------------------------------------------------------------------
// K1: gi = relu(obs @ W_emb + b_emb) @ Wi + bi, stored f16 PRE-SCALED.
// M=64 tile. 256 blocks x 16 iters. 8 waves = 8 col-groups of 16.
//   gRZ[row*256 + cg*32 + quad*8 + {0..3: SC_R*r, 4..7: SC_R*z}]
//   gN [row*128 + col] = SC_N * n
// (unchanged from r8 — measured ~140 us; counters next round before touching)
// ---------------------------------------------------------------------------
__global__ __launch_bounds__(512) void k1_embed_gi(
    const float* __restrict__ obs,
    const float* __restrict__ W_emb,
    const float* __restrict__ b_emb,
    const float* __restrict__ Wi,
    const float* __restrict__ bi,
    _Float16* __restrict__ gRZ,
    _Float16* __restrict__ gN)
{
    __shared__ __align__(16) _Float16 obs_lds[64 * LDSS];   // 17408 B
    __shared__ __align__(16) _Float16 emb_lds[64 * LDSS];   // 17408 B
    const int tid  = threadIdx.x;
    const int cg   = tid >> 6;     // wave = col-group
    const int lane = tid & 63;
    const int n16  = lane & 15;
    const int quad = lane >> 4;

    // A-frags: lane holds A[m=n16][k=kt*32+quad*8+j]; gate scales folded in.
    v8h fe[4];
    v8h fi[3][4];
#pragma unroll
    for (int kt = 0; kt < 4; ++kt)
#pragma unroll
        for (int j = 0; j < 8; ++j) {
            const int k = kt * 32 + quad * 8 + j;
            fe[kt][j] = (_Float16)W_emb[k * H_DIM + cg * 16 + n16];
        }
#pragma unroll
    for (int g = 0; g < 3; ++g) {
        const float sc = (g == 2) ? SC_N : SC_R;
#pragma unroll
        for (int kt = 0; kt < 4; ++kt)
#pragma unroll
            for (int j = 0; j < 8; ++j) {
                const int k = kt * 32 + quad * 8 + j;
                fi[g][kt][j] = (_Float16)(Wi[k * G3 + g * H_DIM + cg * 16 + n16] * sc);
            }
    }
    float bemb[4], bir[4], biz[4], bin_[4];
#pragma unroll
    for (int r = 0; r < 4; ++r) {
        const int col = cg * 16 + quad * 4 + r;
        bemb[r] = b_emb[col];
        bir[r]  = bi[col] * SC_R;
        biz[r]  = bi[H_DIM + col] * SC_R;
        bin_[r] = bi[2 * H_DIM + col] * SC_N;
    }

    const int srow = tid >> 3;          // 0..63
    const int sk   = (tid & 7) * 16;    // 0..112 (16 floats per thread)
    const int base = blockIdx.x * 16;   // 16 tiles of 64 rows

    // stage iter 0's obs
    {
        const float* op = obs + (size_t)(base * 64 + srow) * OBS_DIM + sk;
#pragma unroll
        for (int q = 0; q < 4; ++q) {
            const float4 a = *(const float4*)(op + q * 4);
            v4h pa = { (_Float16)a.x, (_Float16)a.y, (_Float16)a.z, (_Float16)a.w };
            *(v4h*)&obs_lds[srow * LDSS + sk + q * 4] = pa;
        }
    }
    __syncthreads();

    for (int i = 0; i < 16; ++i) {
        const int row0 = (base + i) * 64;
        const int ni = (i + 1 < 16) ? i + 1 : i;
        const float* opn = obs + (size_t)((base + ni) * 64 + srow) * OBS_DIM + sk;
        float4 nv[4];
#pragma unroll
        for (int q = 0; q < 4; ++q) nv[q] = *(const float4*)(opn + q * 4);

        // phase A: emb, 4 row-tiles x 16 cols per wave
#pragma unroll
        for (int rt = 0; rt < 4; ++rt) {
            v8h bo[4];
#pragma unroll
            for (int kt = 0; kt < 4; ++kt)
                bo[kt] = *(const v8h*)&obs_lds[(rt * 16 + n16) * LDSS + kt * 32 + quad * 8];
            v4f ea = {0.f, 0.f, 0.f, 0.f};
#pragma unroll
            for (int kt = 0; kt < 4; ++kt)
                ea = __builtin_amdgcn_mfma_f32_16x16x32_f16(fe[kt], bo[kt], ea, 0, 0, 0);
            v4h e;
#pragma unroll
            for (int r = 0; r < 4; ++r) e[r] = (_Float16)fmaxf(ea[r] + bemb[r], 0.f);
            *(v4h*)&emb_lds[(rt * 16 + n16) * LDSS + cg * 16 + quad * 4] = e;
        }
        BAR();
        // phase B: gi, 4 row-tiles x 3 gates x 16 cols per wave
#pragma unroll
        for (int rt = 0; rt < 4; ++rt) {
            v8h be[4];
#pragma unroll
            for (int kt = 0; kt < 4; ++kt)
                be[kt] = *(const v8h*)&emb_lds[(rt * 16 + n16) * LDSS + kt * 32 + quad * 8];
            v4f ar = {0.f,0.f,0.f,0.f}, az = {0.f,0.f,0.f,0.f}, an = {0.f,0.f,0.f,0.f};
#pragma unroll
            for (int kt = 0; kt < 4; ++kt) {
                ar = __builtin_amdgcn_mfma_f32_16x16x32_f16(fi[0][kt], be[kt], ar, 0, 0, 0);
                az = __builtin_amdgcn_mfma_f32_16x16x32_f16(fi[1][kt], be[kt], az, 0, 0, 0);
                an = __builtin_amdgcn_mfma_f32_16x16x32_f16(fi[2][kt], be[kt], an, 0, 0, 0);
            }
            const int R = row0 + rt * 16 + n16;
            v8h rz;
#pragma unroll
            for (int r = 0; r < 4; ++r) {
                rz[r]     = (_Float16)(ar[r] + bir[r]);
                rz[4 + r] = (_Float16)(az[r] + biz[r]);
            }
            *(v8h*)&gRZ[(size_t)R * 256 + cg * 32 + quad * 8] = rz;
            v4h nn;
#pragma unroll
            for (int r = 0; r < 4; ++r) nn[r] = (_Float16)(an[r] + bin_[r]);
            *(v4h*)&gN[(size_t)R * 128 + cg * 16 + quad * 4] = nn;
        }
        // stage next iter's obs (obs_lds reads all ended before the mid BAR)
#pragma unroll
        for (int q = 0; q < 4; ++q) {
            v4h pa = { (_Float16)nv[q].x, (_Float16)nv[q].y, (_Float16)nv[q].z, (_Float16)nv[q].w };
            *(v4h*)&obs_lds[srow * LDSS + sk + q * 4] = pa;
        }
        BAR();
    }
}

// ---------------------------------------------------------------------------
// K2: GRU recurrence + fused q epilogue. 32 blocks x 16 batch rows, 8 waves.
// Loop identical to r8 (417 us). Epilogue: each block computes q for its OWN
// 16 batch rows x all 512 t from the gN/ys slice it just wrote (L2-resident,
// no cross-block dependency). Wave w covers t in [64w, 64w+64).
// ---------------------------------------------------------------------------
__global__ __launch_bounds__(512) void k2_recurrence(
    const float* __restrict__ hidden,
    const unsigned char* __restrict__ dones_raw,
    const _Float16* __restrict__ gRZ,
    _Float16* __restrict__ gN,
    const float* __restrict__ Wh,
    const float* __restrict__ bhn,
    const float* __restrict__ W_out,
    const float* __restrict__ b_out,
    float* __restrict__ out)
{
    __shared__ __align__(16) _Float16 h_lds[2][16 * LDSS];
    __shared__ __align__(16) unsigned char d_lds[(T_DIM + 1) * 16];
    __shared__ int byte_mode;
    const int tid  = threadIdx.x;
    const int w    = tid >> 6;
    const int lane = tid & 63;
    const int n16  = lane & 15;   // batch within group
    const int quad = lane >> 4;
    const int c16  = w * 16 + quad * 4;
    const int B0   = blockIdx.x * 16;

    if (tid == 0) byte_mode = 0;
    __syncthreads();
    {   // detect dones element width: byte==1 at non-4-aligned offset => 1-byte bools
        int hit = 0;
        for (int i = tid; i < 4096; i += 512)
            if ((i & 3) != 0 && dones_raw[i] == 1) hit = 1;
        if (hit) byte_mode = 1;
    }
    __syncthreads();
    const bool bm = (byte_mode != 0);

    // stage this block's dones slice: d_lds[t*16 + b]; row T zeroed
    {
        if (bm) {
            const int4 v = *(const int4*)(dones_raw + (size_t)tid * B_DIM + B0);
            *(int4*)&d_lds[tid * 16] = v;
        } else {
            const int* di = (const int*)dones_raw;
            const int* pp = di + (size_t)tid * B_DIM + B0;
            int4 wv; unsigned char* wb = (unsigned char*)&wv;
#pragma unroll
            for (int j = 0; j < 16; ++j) wb[j] = (unsigned char)(pp[j] != 0);
            *(int4*)&d_lds[tid * 16] = wv;
        }
        if (tid == 0) { int4 z = {0,0,0,0}; *(int4*)&d_lds[T_DIM * 16] = z; }
    }

    // Wh^T A-frags, gate scales folded in
    v8h fh[3][4];
#pragma unroll
    for (int g = 0; g < 3; ++g) {
        const float sc = (g == 2) ? SC_N : SC_R;
#pragma unroll
        for (int kt = 0; kt < 4; ++kt)
#pragma unroll
            for (int j = 0; j < 8; ++j) {
                const int k = kt * 32 + quad * 8 + j;
                fh[g][kt][j] = (_Float16)(Wh[k * G3 + g * H_DIM + w * 16 + n16] * sc);
            }
    }
    float bhnr[4];
#pragma unroll
    for (int r = 0; r < 4; ++r) bhnr[r] = bhn[c16 + r] * SC_N;

    __syncthreads();   // d_lds visible

    // init carry, pre-masked with done[0]
    const bool d0 = d_lds[n16] != 0;
    float hu[4];
#pragma unroll
    for (int r = 0; r < 4; ++r) {
        const float hv = hidden[(size_t)(B0 + n16) * H_DIM + c16 + r];
        hu[r] = d0 ? 0.f : hv;
    }
    {
        v4h hw = { (_Float16)hu[0], (_Float16)hu[1], (_Float16)hu[2], (_Float16)hu[3] };
        *(v4h*)&h_lds[0][n16 * LDSS + c16] = hw;
    }

    const size_t RZT = (size_t)B_DIM * 256;
    const size_t NT  = (size_t)B_DIM * 128;
    const _Float16* rzp = gRZ + (size_t)(B0 + n16) * 256 + w * 32 + quad * 8;
    _Float16*       np  = gN  + (size_t)(B0 + n16) * 128 + c16;

    // preload t=0,1; running prefetch pointers at t=2
    v8h s8_0 = *(const v8h*)(rzp);
    v4h s4_0 = *(const v4h*)(np);
    v8h s8_1 = *(const v8h*)(rzp + RZT);
    v4h s4_1 = *(const v4h*)(np + NT);
    const _Float16* pf8 = rzp + 2 * RZT;
    const _Float16* pf4 = np + 2 * NT;
    _Float16* yp = np;                 // ys store pointer (row t)
    const unsigned char* dp = &d_lds[16 + n16];   // done[t+1]
    __syncthreads();   // h_lds[0] visible

    auto STEP = [&](int t, v8h& s8, v4h& s4, const _Float16* hin, _Float16* hout)
        __attribute__((always_inline)) -> void {
        // prefetch t+2 from running pointers (stays in flight across BAR)
        const v8h gC8 = *(const v8h*)pf8;
        const v4h gC4 = *(const v4h*)pf4;
        const unsigned char dnx = *dp;

        v8h bh[4];
#pragma unroll
        for (int kt = 0; kt < 4; ++kt)
            bh[kt] = *(const v8h*)&hin[n16 * LDSS + kt * 32 + quad * 8];

        v4f ga0 = {0.f,0.f,0.f,0.f}, ga1 = {0.f,0.f,0.f,0.f}, ga2 = {0.f,0.f,0.f,0.f};
#pragma unroll
        for (int kt = 0; kt < 4; ++kt) {
            ga0 = __builtin_amdgcn_mfma_f32_16x16x32_f16(fh[0][kt], bh[kt], ga0, 0, 0, 0);
            ga1 = __builtin_amdgcn_mfma_f32_16x16x32_f16(fh[1][kt], bh[kt], ga1, 0, 0, 0);
            ga2 = __builtin_amdgcn_mfma_f32_16x16x32_f16(fh[2][kt], bh[kt], ga2, 0, 0, 0);
        }

        // fused gates: h = [ez*(en-1) + hu*(en+1)] / [(en+1)*(1+ez)]
        float hn[4];
#pragma unroll
        for (int r = 0; r < 4; ++r) {
            const float er = EXP2F((float)s8[r] + ga0[r]);
            const float rg = RCPF(1.f + er);
            const float sn = fmaf(rg, ga2[r] + bhnr[r], (float)s4[r]);
            const float en = EXP2F(sn);
            const float ez = EXP2F((float)s8[4 + r] + ga1[r]);
            const float enp = en + 1.f;
            const float num = fmaf(hu[r], enp, (en - 1.f) * ez);
            const float den = enp * (1.f + ez);
            hn[r] = num * RCPF(den);
        }

        // ys[t] (unmasked) -> gN row t (already consumed)
        v4h yv = { (_Float16)hn[0], (_Float16)hn[1], (_Float16)hn[2], (_Float16)hn[3] };
        *(v4h*)yp = yv;

        // mask with done[t+1] at write
        const bool dn = dnx != 0;
        v4h hz = { (_Float16)0.f, (_Float16)0.f, (_Float16)0.f, (_Float16)0.f };
        v4h hv = dn ? hz : yv;
#pragma unroll
        for (int r = 0; r < 4; ++r) hu[r] = dn ? 0.f : hn[r];
        *(v4h*)&hout[n16 * LDSS + c16] = hv;

        s8 = gC8; s4 = gC4;
        // advance running pointers; stop pf at row 511 (uniform scalar select)
        const size_t adv = (t < 509) ? 1 : 0;
        pf8 += adv * RZT; pf4 += adv * NT;
        yp += NT; dp += 16;
        BAR();
    };

    for (int t = 0; t < T_DIM; t += 2) {
        STEP(t,     s8_0, s4_0, h_lds[0], h_lds[1]);
        STEP(t + 1, s8_1, s4_1, h_lds[1], h_lds[0]);
    }

    // h_final (hu after t=511 is unmasked: d_lds row 512 zeroed)
#pragma unroll
    for (int r = 0; r < 4; ++r)
        out[(size_t)(B0 + n16) * H_DIM + c16 + r] = hu[r];

    // ================= q epilogue: q = ys @ W_out + b_out =================
    // Block-local: rows (t, B0+n16) for all t; wave w covers t in [64w,64w+64).
    __syncthreads();   // all waves' ys stores complete & visible block-wide

    v8h fo[2][4];
#pragma unroll
    for (int ct = 0; ct < 2; ++ct)
#pragma unroll
        for (int kt = 0; kt < 4; ++kt)
#pragma unroll
            for (int j = 0; j < 8; ++j) {
                const int k = kt * 32 + quad * 8 + j;
                const int col = ct * 16 + n16;
                fo[ct][kt][j] = (col < A_DIM) ? (_Float16)W_out[k * A_DIM + col] : (_Float16)0.f;
            }
    float bq0[4], bq1[4];
#pragma unroll
    for (int r = 0; r < 4; ++r) {
        const int c0 = quad * 4 + r;
        const int c1 = 16 + quad * 4 + r;
        bq0[r] = b_out[c0];                       // c0 <= 15 < 18
        bq1[r] = (c1 < A_DIM) ? b_out[c1] : 0.f;
    }
    float* qout = out + (size_t)B_DIM * H_DIM;
    const _Float16* yrow = gN + ((size_t)(w * 64) * B_DIM + B0 + n16) * 128;
    float* qp = qout + ((size_t)(w * 64) * B_DIM + B0 + n16) * A_DIM;

    for (int i = 0; i < 64; ++i) {
        v8h by[4];
#pragma unroll
        for (int kt = 0; kt < 4; ++kt)
            by[kt] = *(const v8h*)(yrow + kt * 32 + quad * 8);
        v4f q0 = {0.f,0.f,0.f,0.f}, q1 = {0.f,0.f,0.f,0.f};
#pragma unroll
        for (int kt = 0; kt < 4; ++kt) {
            q0 = __builtin_amdgcn_mfma_f32_16x16x32_f16(fo[0][kt], by[kt], q0, 0, 0, 0);
            q1 = __builtin_amdgcn_mfma_f32_16x16x32_f16(fo[1][kt], by[kt], q1, 0, 0, 0);
        }
#pragma unroll
        for (int r = 0; r < 4; ++r) qp[quad * 4 + r] = q0[r] + bq0[r];
        if (quad == 0) {
#pragma unroll
            for (int r = 0; r < 2; ++r) qp[16 + r] = q1[r] + bq1[r];
        }
        yrow += (size_t)B_DIM * 128;
        qp   += (size_t)B_DIM * A_DIM;
    }
}

extern "C" void kernel_launch(void* const* d_in, const int* in_sizes, int n_in,
                              void* d_out, int out_size, void* d_ws, size_t ws_size,
                              hipStream_t stream) {
    const float* hidden = (const float*)d_in[0];
    const float* obs    = (const float*)d_in[1];
    const unsigned char* dones = (const unsigned char*)d_in[2];
    const float* W_emb  = (const float*)d_in[3];
    const float* b_emb  = (const float*)d_in[4];
    const float* Wi     = (const float*)d_in[5];
    const float* bi     = (const float*)d_in[6];
    const float* Wh     = (const float*)d_in[7];
    const float* bhn    = (const float*)d_in[8];
    const float* W_out  = (const float*)d_in[9];
    const float* b_out  = (const float*)d_in[10];
    float* out = (float*)d_out;

    _Float16* gRZ = (_Float16*)d_ws;                              // [T*B][256] f16 = 128 MiB
    _Float16* gN  = gRZ + (size_t)T_DIM * B_DIM * 256;            // [T*B][128] f16 =  64 MiB

    hipLaunchKernelGGL(k1_embed_gi, dim3(256), dim3(512), 0, stream,
                       obs, W_emb, b_emb, Wi, bi, gRZ, gN);
    hipLaunchKernelGGL(k2_recurrence, dim3(32), dim3(512), 0, stream,
                       hidden, dones, gRZ, gN, Wh, bhn, W_out, b_out, out);
}